// Round 5
// baseline (178.686 us; speedup 1.0000x reference)
//
#include <hip/hip_runtime.h>
#include <hip/hip_fp16.h>

#define BB    32
#define CIN   256
#define COUT  256
#define HH    28
#define WW    28
#define NPIX  784
#define KD    2304            // 9 * 256
#define HP    30
#define WP    30

#define BM    128
#define BN    128
#define NT    7               // ceil(784/128)

// workspace: wgen [b][o][khw][c] f16 (18.87M elems), xpad [b][30][30][256] f16
#define WGEN_ELEMS ((size_t)BB * COUT * KD)
#define XPAD_OFF   (WGEN_ELEMS)

// fused prep block ranges
#define PREP_GENW  2048
#define PREP_GENX  960
#define PREP_INIT  448
#define PREP_GRID  (PREP_GENW + PREP_GENX + PREP_INIT)

typedef _Float16 f16x8 __attribute__((ext_vector_type(8)));
typedef float    f32x4 __attribute__((ext_vector_type(4)));

static __device__ __forceinline__ ushort f2h_bits(float v) {
    __half h = __float2half(v);
    return *reinterpret_cast<ushort*>(&h);
}

static __device__ __forceinline__ void gll16(const ushort* g, ushort* l) {
    __builtin_amdgcn_global_load_lds(
        (const __attribute__((address_space(1))) unsigned int*)g,
        (__attribute__((address_space(3))) unsigned int*)l, 16, 0, 0);
}

// ---------------------------------------------------------------------------
// Fused prep kernel: one launch, three roles by blockIdx.
//   [0, 2048)          : gen_w  -> wgen[b][o][khw][c] f16 (8 b-groups x 256 o)
//   [2048, 3008)       : gen_x  -> xpad[b][30][30][256] f16, zero-padded
//   [3008, 3456)       : out = bias (split-K dconv accumulates via atomics)
// ---------------------------------------------------------------------------
__global__ __launch_bounds__(256) void prep(const float* __restrict__ weight,
                                            const float* __restrict__ se,
                                            const float* __restrict__ x,
                                            const float* __restrict__ bias,
                                            ushort* __restrict__ wgen,
                                            ushort* __restrict__ xpad,
                                            float* __restrict__ out) {
    __shared__ __align__(16) char smem[29696];
    const int bid = blockIdx.x;
    const int tid = threadIdx.x;

    if (bid < PREP_GENW) {
        // ---- gen_w ----
        const int o  = bid & 255;
        const int bg = bid >> 8;
        float*  se_sh = (float*)smem;            // 1024 B
        ushort* w_sh  = (ushort*)(smem + 1024);  // 4608 B
        const int c = tid;

        se_sh[c] = se[c];
        float4 wr[18];
        const float4* wp = (const float4*)(weight + (size_t)(o * CIN + c) * 9 * 8);
#pragma unroll
        for (int i = 0; i < 18; ++i) wr[i] = wp[i];
        __syncthreads();

#pragma unroll
        for (int bi = 0; bi < 4; ++bi) {
            const int b = bg * 4 + bi;
            const float s0 = se_sh[b * 8 + 0], s1 = se_sh[b * 8 + 1];
            const float s2 = se_sh[b * 8 + 2], s3 = se_sh[b * 8 + 3];
            const float s4 = se_sh[b * 8 + 4], s5 = se_sh[b * 8 + 5];
            const float s6 = se_sh[b * 8 + 6], s7 = se_sh[b * 8 + 7];
#pragma unroll
            for (int khw = 0; khw < 9; ++khw) {
                const float4 w0 = wr[khw * 2 + 0];
                const float4 w1 = wr[khw * 2 + 1];
                const float v = w0.x * s0 + w0.y * s1 + w0.z * s2 + w0.w * s3
                              + w1.x * s4 + w1.y * s5 + w1.z * s6 + w1.w * s7;
                w_sh[khw * 256 + c] = f2h_bits(v);
            }
            __syncthreads();
            const uint4* src = (const uint4*)w_sh;
            uint4* dst = (uint4*)(wgen + ((size_t)b * COUT + o) * KD);
            dst[c] = src[c];
            if (c < 32) dst[256 + c] = src[256 + c];
            __syncthreads();
        }
    } else if (bid < PREP_GENW + PREP_GENX) {
        // ---- gen_x ----
        const int idx = bid - PREP_GENW;
        const int hp  = idx % HP;
        const int b   = idx / HP;
        ushort* row = xpad + ((size_t)b * HP + hp) * WP * CIN;

        if (hp == 0 || hp == HP - 1) {
            uint* r32 = (uint*)row;
            for (int i = tid; i < (WP * CIN) / 2; i += 256) r32[i] = 0u;
            return;
        }
        {
            uint* c0 = (uint*)row;
            uint* c1 = (uint*)(row + (WP - 1) * CIN);
            if (tid < 128)       c0[tid] = 0u;
            else                 c1[tid - 128] = 0u;
        }
        float* lds = (float*)smem;               // 256*29*4 = 29696 B
        const int h = hp - 1;
        const float* xr = x + (size_t)b * CIN * NPIX + h * WW;

        for (int f = tid; f < CIN * WW; f += 256) {
            const int c = f / WW;
            const int w = f % WW;
            lds[c * (WW + 1) + w] = xr[(size_t)c * NPIX + w];
        }
        __syncthreads();
        for (int g2 = tid; g2 < WW * CIN; g2 += 256) {
            const int w = g2 >> 8;
            const int c = g2 & 255;
            row[(w + 1) * CIN + c] = f2h_bits(lds[c * (WW + 1) + w]);
        }
    } else {
        // ---- out = bias ----
        const int idx = bid - PREP_GENW - PREP_GENX;   // 0..447
        float4* o4 = (float4*)out;
        const int total4 = BB * COUT * NPIX / 4;       // 1,605,632
        for (int i = idx * 256 + tid; i < total4; i += PREP_INIT * 256) {
            const int o = (i / (NPIX / 4)) & (COUT - 1);
            const float bv = bias[o];
            o4[i] = (float4){bv, bv, bv, bv};
        }
    }
}

// ---------------------------------------------------------------------------
// Kernel 2: implicit-GEMM conv, split-K 2-way.
// Per sample: M=256(o), N=784(p), K=2304 split into two K=1152 halves.
// Block tile 128x128, wave 64x64; grid = 32*2*7*2 = 896 (3.5 blocks/CU).
// K-loop: 4 c32 chunks x 9 khw; shifted-window patch staged once per c32.
// Single-buffer Ash/Psh, 2-barrier per step (m97 structure). Epilogue:
// unsafeAtomicAdd partials onto bias-initialized out.
// ---------------------------------------------------------------------------
__global__ __launch_bounds__(256) void dconv_mfma(const ushort* __restrict__ wgen,
                                                  const ushort* __restrict__ xpad,
                                                  float* __restrict__ out) {
    // XCD remap: all 14 (nt, ks) blocks of a (b,mt) slice on one XCD.
    const int bid   = blockIdx.x;
    const int g     = bid & 7;
    const int s     = bid >> 3;            // 0..111
    const int t     = s % 14;
    const int nt    = t % 7;
    const int ks    = t / 7;               // 0/1: K half
    const int slice = g + 8 * (s / 14);    // 0..63 = b*2 + mt
    const int b     = slice >> 1;
    const int mt    = slice & 1;

    const int tid  = threadIdx.x;
    const int lane = tid & 63;
    const int wave = tid >> 6;
    const int wm   = wave >> 1;
    const int wn   = wave & 1;
    const int col  = lane & 15;
    const int quad = lane >> 4;

    __shared__ ushort Ash[BM * 32];        // 8192 B
    __shared__ ushort Psh[4 * 8 * 30 * 8]; // 15360 B

    const int mo   = mt * BM + wm * 64;
    const int no   = nt * BN + wn * 64;
    const int h_lo = (nt * BN) / WW;

    const ushort* wg = wgen + ((size_t)b * COUT + mt * BM) * KD;
    const ushort* xp = xpad + (size_t)b * HP * WP * CIN;

    // staging offsets (khw/c32-independent parts)
    int a_goff[2], a_loff[2];
#pragma unroll
    for (int r = 0; r < 2; ++r) {
        const int cch = r * 256 + tid;
        const int m   = cch >> 2;
        const int kc  = (cch & 3) ^ ((m >> 1) & 3);
        a_goff[r] = m * 9 * CIN + kc * 8;
        a_loff[r] = cch * 8;
    }
    int p_goff[4], p_loff[4];
    bool p_ok[4];
#pragma unroll
    for (int r = 0; r < 4; ++r) {
        const int j = r * 256 + tid;
        p_ok[r] = (j < 960);
        const int jj  = p_ok[r] ? j : 0;
        const int qc  = jj / 240;
        const int rem = jj % 240;
        const int rr  = rem / 30;
        const int ww  = rem % 30;
        int srow = h_lo + rr;
        if (srow > 29) srow = 29;
        p_goff[r] = (srow * WP + ww) * CIN + qc * 8;
        p_loff[r] = jj * 8;
    }

    int pixbase[4], pst[4];
#pragma unroll
    for (int j = 0; j < 4; ++j) {
        const int p  = no + j * 16 + col;
        pst[j] = p;
        const int pc = p > (NPIX - 1) ? (NPIX - 1) : p;
        pixbase[j] = (pc / WW - h_lo) * 30 + (pc % WW);
    }
    const int s_sw  = (col >> 1) & 3;
    const int abase = ((wm * 64 + col) << 2) + (quad ^ s_sw);

    f32x4 acc[4][4];
#pragma unroll
    for (int mi = 0; mi < 4; ++mi)
#pragma unroll
        for (int nj = 0; nj < 4; ++nj)
            acc[mi][nj] = (f32x4){0.f, 0.f, 0.f, 0.f};

    for (int cc = 0; cc < 4; ++cc) {
        const int c32  = ks * 4 + cc;
        const int coff = c32 * 32;
        __syncthreads();   // everyone done reading Psh/Ash from prev chunk

        // stage patch for this c32
#pragma unroll
        for (int r = 0; r < 4; ++r)
            if (p_ok[r]) gll16(xp + p_goff[r] + coff, Psh + p_loff[r]);
        // stage A for khw=0
#pragma unroll
        for (int r = 0; r < 2; ++r)
            gll16(wg + a_goff[r] + coff, Ash + a_loff[r]);

#pragma unroll
        for (int khw = 0; khw < 9; ++khw) {
            if (khw > 0) {
                __syncthreads();
#pragma unroll
                for (int r = 0; r < 2; ++r)
                    gll16(wg + a_goff[r] + khw * 256 + coff, Ash + a_loff[r]);
            }
            __syncthreads();

            const int koff = (khw / 3) * 30 + (khw % 3);

            f16x8 af[4];
#pragma unroll
            for (int sub = 0; sub < 4; ++sub)
                af[sub] = ((const f16x8*)Ash)[abase + sub * 64];

            f16x8 bf[4];
#pragma unroll
            for (int j = 0; j < 4; ++j)
                bf[j] = ((const f16x8*)Psh)[quad * 240 + pixbase[j] + koff];

#pragma unroll
            for (int mi = 0; mi < 4; ++mi)
#pragma unroll
                for (int nj = 0; nj < 4; ++nj)
                    acc[mi][nj] = __builtin_amdgcn_mfma_f32_16x16x32_f16(
                        af[mi], bf[nj], acc[mi][nj], 0, 0, 0);
        }
    }

    // epilogue: accumulate partials (out pre-initialized to bias)
    float* ob = out + (size_t)b * COUT * NPIX;
#pragma unroll
    for (int mi = 0; mi < 4; ++mi) {
        const int m = mo + mi * 16 + quad * 4;
#pragma unroll
        for (int nj = 0; nj < 4; ++nj) {
            const int p = pst[nj];
            if (p < NPIX) {
#pragma unroll
                for (int r = 0; r < 4; ++r)
                    unsafeAtomicAdd(&ob[(size_t)(m + r) * NPIX + p], acc[mi][nj][r]);
            }
        }
    }
}

extern "C" void kernel_launch(void* const* d_in, const int* in_sizes, int n_in,
                              void* d_out, int out_size, void* d_ws, size_t ws_size,
                              hipStream_t stream) {
    const float* x      = (const float*)d_in[0];
    const float* se     = (const float*)d_in[1];
    const float* weight = (const float*)d_in[2];
    const float* bias   = (const float*)d_in[3];
    float* out          = (float*)d_out;

    ushort* wgen = (ushort*)d_ws;
    ushort* xpad = (ushort*)d_ws + XPAD_OFF;
    (void)ws_size; (void)in_sizes; (void)n_in; (void)out_size;

    prep<<<dim3(PREP_GRID), dim3(256), 0, stream>>>(weight, se, x, bias, wgen, xpad, out);
    dconv_mfma<<<dim3(BB * 2 * NT * 2), dim3(256), 0, stream>>>(wgen, xpad, out);
}

// Round 8
// 177.816 us; speedup vs baseline: 1.0049x; 1.0049x over previous
//
#include <hip/hip_runtime.h>
#include <hip/hip_fp16.h>

#define BB    32
#define CIN   256
#define COUT  256
#define HH    28
#define WW    28
#define NPIX  784
#define HP    30
#define WP    30

#define BM    128
#define BN    128
#define NT    7               // ceil(784/128)

// workspace:
//   wgen2: fragment-ordered filters, per (b,mt) slice 294912 f16 elems
//          (= 128 m-rows x 2304 K). Chunk index (in 8-f16 units):
//          (c32*9 + khw)*512 + sub*64 + quad*16 + col
//          holds A[m = mt*128 + sub*16 + col][ch = c32*32 + quad*8 .. +7] @ tap khw
//   xpad : [b][30][30][256] f16 zero-padded NHWC
#define SLICE_ELEMS 294912                       // 128 * 2304
#define WGEN_ELEMS  ((size_t)BB * 2 * SLICE_ELEMS)
#define XPAD_OFF    (WGEN_ELEMS)

#define PREP_GENW  2048
#define PREP_GENX  960
#define PREP_GRID  (PREP_GENW + PREP_GENX)

typedef _Float16 f16x8 __attribute__((ext_vector_type(8)));
typedef float    f32x4 __attribute__((ext_vector_type(4)));

static __device__ __forceinline__ ushort f2h_bits(float v) {
    __half h = __float2half(v);
    return *reinterpret_cast<ushort*>(&h);
}

static __device__ __forceinline__ void gll16(const ushort* g, ushort* l) {
    __builtin_amdgcn_global_load_lds(
        (const __attribute__((address_space(1))) unsigned int*)g,
        (__attribute__((address_space(3))) unsigned int*)l, 16, 0, 0);
}

// ---------------------------------------------------------------------------
// Fused prep kernel.
//   [0, 2048)    : gen_w -> wgen2 fragment-ordered f16 (8 b-groups x 256 o)
//   [2048, 3008) : gen_x -> xpad f16 zero-padded NHWC
// ---------------------------------------------------------------------------
__global__ __launch_bounds__(256) void prep(const float* __restrict__ weight,
                                            const float* __restrict__ se,
                                            const float* __restrict__ x,
                                            ushort* __restrict__ wgen2,
                                            ushort* __restrict__ xpad) {
    __shared__ __align__(16) char smem[29696];
    const int bid = blockIdx.x;
    const int tid = threadIdx.x;

    if (bid < PREP_GENW) {
        // ---- gen_w ----
        const int o  = bid & 255;
        const int bg = bid >> 8;
        const int mt  = o >> 7;
        const int sub = (o >> 4) & 7;
        const int col = o & 15;
        float*  se_sh = (float*)smem;            // 1024 B
        ushort* w_sh  = (ushort*)(smem + 1024);  // 4608 B
        const int c = tid;

        se_sh[c] = se[c];
        float4 wr[18];
        const float4* wp = (const float4*)(weight + (size_t)(o * CIN + c) * 9 * 8);
#pragma unroll
        for (int i = 0; i < 18; ++i) wr[i] = wp[i];
        __syncthreads();

        // 288 chunks per (b,o): chunk j -> (c32=j/36, khw=(j%36)>>2, quad=j&3).
        // Thread tid stores chunk tid; tid<32 also stores chunk 256+tid.
        const int j0 = tid;
        const int c32q0 = j0 / 36, rem0 = j0 % 36;
        const int khwq0 = rem0 >> 2, qq0 = rem0 & 3;
        const int srcq0 = khwq0 * 256 + c32q0 * 32 + qq0 * 8;
        const int dstq0 = ((c32q0 * 9 + khwq0) * 512 + sub * 64 + qq0 * 16 + col) * 8;
        const int j1 = 256 + tid;
        const int c32q1 = j1 / 36, rem1 = j1 % 36;
        const int khwq1 = rem1 >> 2, qq1 = rem1 & 3;
        const int srcq1 = khwq1 * 256 + c32q1 * 32 + qq1 * 8;
        const int dstq1 = ((c32q1 * 9 + khwq1) * 512 + sub * 64 + qq1 * 16 + col) * 8;

#pragma unroll
        for (int bi = 0; bi < 4; ++bi) {
            const int b = bg * 4 + bi;
            const float s0 = se_sh[b * 8 + 0], s1 = se_sh[b * 8 + 1];
            const float s2 = se_sh[b * 8 + 2], s3 = se_sh[b * 8 + 3];
            const float s4 = se_sh[b * 8 + 4], s5 = se_sh[b * 8 + 5];
            const float s6 = se_sh[b * 8 + 6], s7 = se_sh[b * 8 + 7];
#pragma unroll
            for (int khw = 0; khw < 9; ++khw) {
                const float4 w0 = wr[khw * 2 + 0];
                const float4 w1 = wr[khw * 2 + 1];
                const float v = w0.x * s0 + w0.y * s1 + w0.z * s2 + w0.w * s3
                              + w1.x * s4 + w1.y * s5 + w1.z * s6 + w1.w * s7;
                w_sh[khw * 256 + c] = f2h_bits(v);
            }
            __syncthreads();
            ushort* slice_base = wgen2 + (size_t)(b * 2 + mt) * SLICE_ELEMS;
            *(uint4*)(slice_base + dstq0) = *(const uint4*)(w_sh + srcq0);
            if (tid < 32)
                *(uint4*)(slice_base + dstq1) = *(const uint4*)(w_sh + srcq1);
            __syncthreads();
        }
    } else {
        // ---- gen_x ----
        const int idx = bid - PREP_GENW;
        const int hp  = idx % HP;
        const int b   = idx / HP;
        ushort* row = xpad + ((size_t)b * HP + hp) * WP * CIN;

        if (hp == 0 || hp == HP - 1) {
            uint* r32 = (uint*)row;
            for (int i = tid; i < (WP * CIN) / 2; i += 256) r32[i] = 0u;
            return;
        }
        {
            uint* c0 = (uint*)row;
            uint* c1 = (uint*)(row + (WP - 1) * CIN);
            if (tid < 128)       c0[tid] = 0u;
            else                 c1[tid - 128] = 0u;
        }
        float* lds = (float*)smem;               // 256*29*4 = 29696 B
        const int h = hp - 1;
        const float* xr = x + (size_t)b * CIN * NPIX + h * WW;

        for (int f = tid; f < CIN * WW; f += 256) {
            const int c = f / WW;
            const int w = f % WW;
            lds[c * (WW + 1) + w] = xr[(size_t)c * NPIX + w];
        }
        __syncthreads();
        for (int g2 = tid; g2 < WW * CIN; g2 += 256) {
            const int w = g2 >> 8;
            const int c = g2 & 255;
            row[(w + 1) * CIN + c] = f2h_bits(lds[c * (WW + 1) + w]);
        }
    }
}

// ---------------------------------------------------------------------------
// dconv: implicit-GEMM, A direct global->VGPR (fragment-ordered, coalesced
// dwordx4), B via shifted-window LDS patch. Barriers only per c32 chunk:
// 2 barriers per 144 MFMAs. Within a c32, 36 independent A-loads interleave
// with MFMA under compiler vmcnt(N) scheduling (AITER-style, no full drain).
// Block tile 128x128, wave 64x64, grid 448, XCD-grouped.
// ---------------------------------------------------------------------------
__global__ __launch_bounds__(256) void dconv_mfma(const ushort* __restrict__ wgen2,
                                                  const ushort* __restrict__ xpad,
                                                  const float* __restrict__ bias,
                                                  float* __restrict__ out) {
    // XCD remap: all 7 nt of a (b,mt) slice on one XCD.
    const int bid   = blockIdx.x;
    const int g     = bid & 7;
    const int s     = bid >> 3;            // 0..55
    const int nt    = s % NT;
    const int slice = g + 8 * (s / NT);    // 0..63 = b*2 + mt
    const int b     = slice >> 1;
    const int mt    = slice & 1;

    const int tid  = threadIdx.x;
    const int lane = tid & 63;
    const int wave = tid >> 6;
    const int wm   = wave >> 1;
    const int wn   = wave & 1;
    const int col  = lane & 15;
    const int quad = lane >> 4;

    __shared__ ushort Psh[4 * 8 * 30 * 8]; // 15360 B: [quad][row][w][8 f16]

    const int mo   = mt * BM + wm * 64;
    const int no   = nt * BN + wn * 64;
    const int h_lo = (nt * BN) / WW;

    // A: fragment-ordered slice; wave wm reads subs wm*4 + mi
    const f16x8* ag = (const f16x8*)(wgen2 + (size_t)slice * SLICE_ELEMS)
                      + (wm * 4) * 64 + lane;
    const ushort* xp = xpad + (size_t)b * HP * WP * CIN;

    // patch staging offsets (4 chunks/thread, 960 total)
    int p_goff[4], p_loff[4];
    bool p_ok[4];
#pragma unroll
    for (int r = 0; r < 4; ++r) {
        const int j = r * 256 + tid;
        p_ok[r] = (j < 960);
        const int jj  = p_ok[r] ? j : 0;
        const int qc  = jj / 240;
        const int rem = jj % 240;
        const int rr  = rem / 30;
        const int ww  = rem % 30;
        int srow = h_lo + rr;
        if (srow > 29) srow = 29;
        p_goff[r] = (srow * WP + ww) * CIN + qc * 8;
        p_loff[r] = jj * 8;
    }

    int pixbase[4], pst[4];
#pragma unroll
    for (int j = 0; j < 4; ++j) {
        const int p  = no + j * 16 + col;
        pst[j] = p;
        const int pc = p > (NPIX - 1) ? (NPIX - 1) : p;
        pixbase[j] = (pc / WW - h_lo) * 30 + (pc % WW);
    }

    f32x4 acc[4][4];
#pragma unroll
    for (int mi = 0; mi < 4; ++mi)
#pragma unroll
        for (int nj = 0; nj < 4; ++nj)
            acc[mi][nj] = (f32x4){0.f, 0.f, 0.f, 0.f};

    for (int c32 = 0; c32 < 8; ++c32) {
        __syncthreads();                     // everyone done reading Psh

#pragma unroll
        for (int r = 0; r < 4; ++r)
            if (p_ok[r]) gll16(xp + p_goff[r] + c32 * 32, Psh + p_loff[r]);
        __syncthreads();                     // patch visible

#pragma unroll
        for (int khw = 0; khw < 9; ++khw) {
            const f16x8* a0 = ag + ((c32 * 9 + khw) << 9);
            f16x8 af[4];
#pragma unroll
            for (int mi = 0; mi < 4; ++mi)
                af[mi] = a0[mi * 64];

            const int koff = (khw / 3) * 30 + (khw % 3);
            f16x8 bf[4];
#pragma unroll
            for (int j = 0; j < 4; ++j)
                bf[j] = ((const f16x8*)Psh)[quad * 240 + pixbase[j] + koff];

#pragma unroll
            for (int mi = 0; mi < 4; ++mi)
#pragma unroll
                for (int nj = 0; nj < 4; ++nj)
                    acc[mi][nj] = __builtin_amdgcn_mfma_f32_16x16x32_f16(
                        af[mi], bf[nj], acc[mi][nj], 0, 0, 0);
        }
    }

    // epilogue: plain stores + bias
    float* ob = out + (size_t)b * COUT * NPIX;
#pragma unroll
    for (int mi = 0; mi < 4; ++mi) {
        const int m = mo + mi * 16 + quad * 4;
        const float4 bv = *(const float4*)(bias + m);
#pragma unroll
        for (int nj = 0; nj < 4; ++nj) {
            const int p = pst[nj];
            if (p < NPIX) {
                ob[(size_t)(m + 0) * NPIX + p] = acc[mi][nj][0] + bv.x;
                ob[(size_t)(m + 1) * NPIX + p] = acc[mi][nj][1] + bv.y;
                ob[(size_t)(m + 2) * NPIX + p] = acc[mi][nj][2] + bv.z;
                ob[(size_t)(m + 3) * NPIX + p] = acc[mi][nj][3] + bv.w;
            }
        }
    }
}

extern "C" void kernel_launch(void* const* d_in, const int* in_sizes, int n_in,
                              void* d_out, int out_size, void* d_ws, size_t ws_size,
                              hipStream_t stream) {
    const float* x      = (const float*)d_in[0];
    const float* se     = (const float*)d_in[1];
    const float* weight = (const float*)d_in[2];
    const float* bias   = (const float*)d_in[3];
    float* out          = (float*)d_out;

    ushort* wgen2 = (ushort*)d_ws;
    ushort* xpad  = (ushort*)d_ws + XPAD_OFF;
    (void)ws_size; (void)in_sizes; (void)n_in; (void)out_size;

    prep<<<dim3(PREP_GRID), dim3(256), 0, stream>>>(weight, se, x, wgen2, xpad);
    dconv_mfma<<<dim3(BB * 2 * NT), dim3(256), 0, stream>>>(wgen2, xpad, bias, out);
}

// Round 9
// 151.847 us; speedup vs baseline: 1.1768x; 1.1710x over previous
//
#include <hip/hip_runtime.h>
#include <hip/hip_fp16.h>

#define BB    32
#define CIN   256
#define COUT  256
#define HH    28
#define WW    28
#define NPIX  784
#define HP    30
#define WP    30

#define BM    128
#define BN    128
#define NT    7               // ceil(784/128)

// workspace:
//   wgen2: fragment-ordered filters, per (b,mt) slice 294912 f16 elems
//          (= 128 m-rows x 2304 K). Chunk index (in 8-f16 units):
//          (c32*9 + khw)*512 + sub*64 + quad*16 + col
//          holds A[m = mt*128 + sub*16 + col][ch = c32*32 + quad*8 .. +7] @ tap khw
//   xpad : [b][30][30][256] f16 zero-padded NHWC
#define SLICE_ELEMS 294912                       // 128 * 2304
#define WGEN_ELEMS  ((size_t)BB * 2 * SLICE_ELEMS)
#define XPAD_OFF    (WGEN_ELEMS)

#define PREP_GENW  256        // (og 0..31) x (c32 0..7)
#define PREP_GENX  960
#define PREP_GRID  (PREP_GENW + PREP_GENX)

typedef _Float16 f16x8 __attribute__((ext_vector_type(8)));
typedef float    f32x4 __attribute__((ext_vector_type(4)));

static __device__ __forceinline__ ushort f2h_bits(float v) {
    __half h = __float2half(v);
    return *reinterpret_cast<ushort*>(&h);
}

static __device__ __forceinline__ void gll16(const ushort* g, ushort* l) {
    __builtin_amdgcn_global_load_lds(
        (const __attribute__((address_space(1))) unsigned int*)g,
        (__attribute__((address_space(3))) unsigned int*)l, 16, 0, 0);
}

// ---------------------------------------------------------------------------
// Fused prep kernel.
//   [0, 256)    : gen_w V3 -> wgen2 fragment-ordered f16.
//                 Block (og, c32): threads hold weight rows in REGISTERS
//                 (read-once, coalesced); per-b LDS repack; stores in
//                 128-B contiguous runs.
//   [256, 1216) : gen_x -> xpad f16 zero-padded NHWC
// ---------------------------------------------------------------------------
__global__ __launch_bounds__(256) void prep(const float* __restrict__ weight,
                                            const float* __restrict__ se,
                                            const float* __restrict__ x,
                                            ushort* __restrict__ wgen2,
                                            ushort* __restrict__ xpad) {
    __shared__ __align__(16) char smem[29696];
    const int bid = blockIdx.x;
    const int tid = threadIdx.x;

    if (bid < PREP_GENW) {
        // ---- gen_w V3 ----
        const int og  = bid >> 3;            // 0..31 (8 consecutive o)
        const int c32 = bid & 7;             // channel chunk
        const int ol  = tid >> 5;            // o_local 0..7
        const int cl  = tid & 31;            // c_local 0..31
        const int o   = og * 8 + ol;
        const int c   = c32 * 32 + cl;
        const int mt  = o >> 7;
        const int sub = (o >> 4) & 7;
        const int col = o & 15;

        float*  se_sh = (float*)smem;                 // 1024 B
        ushort* w_lds = (ushort*)(smem + 1024);       // [khw*8+ol][40] rows, 11520 B

        se_sh[tid] = se[tid];                         // se[32][8]

        // thread's weight row: 9 taps x 8 num = 72 floats, contiguous
        float4 wr[18];
        const float4* wp = (const float4*)(weight + ((size_t)o * CIN + c) * 72);
#pragma unroll
        for (int i = 0; i < 18; ++i) wr[i] = wp[i];

        // store-phase chunk decomposition (j0 = tid; j1 = 256+tid for tid<32)
        const int khw0 = tid >> 5;                    // j0/32
        const int q0   = (tid >> 3) & 3;
        const int ol0  = tid & 7;
        const int khw1 = 8;                           // (256+tid)/32 for tid<32
        const int q1   = (tid >> 3) & 3;
        const int ol1  = tid & 7;
        const int o0   = og * 8 + ol0;
        const int sub0 = (o0 >> 4) & 7, col0 = o0 & 15;
        const int o1   = og * 8 + ol1;
        const int sub1 = (o1 >> 4) & 7, col1 = o1 & 15;
        const int dst0 = ((c32 * 9 + khw0) * 512 + sub0 * 64 + q0 * 16 + col0) * 8;
        const int dst1 = ((c32 * 9 + khw1) * 512 + sub1 * 64 + q1 * 16 + col1) * 8;
        const int src0 = (khw0 * 8 + ol0) * 40 + q0 * 8;   // ushort idx, 16B-aligned
        const int src1 = (khw1 * 8 + ol1) * 40 + q1 * 8;

        __syncthreads();

        for (int b = 0; b < BB; ++b) {
            const float s0 = se_sh[b * 8 + 0], s1 = se_sh[b * 8 + 1];
            const float s2 = se_sh[b * 8 + 2], s3 = se_sh[b * 8 + 3];
            const float s4 = se_sh[b * 8 + 4], s5 = se_sh[b * 8 + 5];
            const float s6 = se_sh[b * 8 + 6], s7 = se_sh[b * 8 + 7];
#pragma unroll
            for (int k = 0; k < 9; ++k) {
                const float4 w0 = wr[2 * k + 0];
                const float4 w1 = wr[2 * k + 1];
                const float v = w0.x * s0 + w0.y * s1 + w0.z * s2 + w0.w * s3
                              + w1.x * s4 + w1.y * s5 + w1.z * s6 + w1.w * s7;
                w_lds[(k * 8 + ol) * 40 + cl] = f2h_bits(v);
            }
            __syncthreads();
            ushort* slice_base = wgen2 + (size_t)(b * 2 + mt) * SLICE_ELEMS;
            *(uint4*)(slice_base + dst0) = *(const uint4*)(w_lds + src0);
            if (tid < 32)
                *(uint4*)(slice_base + dst1) = *(const uint4*)(w_lds + src1);
            __syncthreads();
        }
    } else {
        // ---- gen_x ----
        const int idx = bid - PREP_GENW;
        const int hp  = idx % HP;
        const int b   = idx / HP;
        ushort* row = xpad + ((size_t)b * HP + hp) * WP * CIN;

        if (hp == 0 || hp == HP - 1) {
            uint* r32 = (uint*)row;
            for (int i = tid; i < (WP * CIN) / 2; i += 256) r32[i] = 0u;
            return;
        }
        {
            uint* c0 = (uint*)row;
            uint* c1 = (uint*)(row + (WP - 1) * CIN);
            if (tid < 128)       c0[tid] = 0u;
            else                 c1[tid - 128] = 0u;
        }
        float* lds = (float*)smem;               // 256*29*4 = 29696 B
        const int h = hp - 1;
        const float* xr = x + (size_t)b * CIN * NPIX + h * WW;

        for (int f = tid; f < CIN * WW; f += 256) {
            const int c = f / WW;
            const int w = f % WW;
            lds[c * (WW + 1) + w] = xr[(size_t)c * NPIX + w];
        }
        __syncthreads();
        for (int g2 = tid; g2 < WW * CIN; g2 += 256) {
            const int w = g2 >> 8;
            const int c = g2 & 255;
            row[(w + 1) * CIN + c] = f2h_bits(lds[c * (WW + 1) + w]);
        }
    }
}

// ---------------------------------------------------------------------------
// dconv: implicit-GEMM, A direct global->VGPR (fragment-ordered, coalesced
// dwordx4), B via shifted-window LDS patch. Barriers only per c32 chunk:
// 2 barriers per 144 MFMAs. Block tile 128x128, wave 64x64, grid 448,
// XCD-grouped. (unchanged from round 8)
// ---------------------------------------------------------------------------
__global__ __launch_bounds__(256) void dconv_mfma(const ushort* __restrict__ wgen2,
                                                  const ushort* __restrict__ xpad,
                                                  const float* __restrict__ bias,
                                                  float* __restrict__ out) {
    const int bid   = blockIdx.x;
    const int g     = bid & 7;
    const int s     = bid >> 3;            // 0..55
    const int nt    = s % NT;
    const int slice = g + 8 * (s / NT);    // 0..63 = b*2 + mt
    const int b     = slice >> 1;
    const int mt    = slice & 1;

    const int tid  = threadIdx.x;
    const int lane = tid & 63;
    const int wave = tid >> 6;
    const int wm   = wave >> 1;
    const int wn   = wave & 1;
    const int col  = lane & 15;
    const int quad = lane >> 4;

    __shared__ ushort Psh[4 * 8 * 30 * 8]; // 15360 B: [quad][row][w][8 f16]

    const int mo   = mt * BM + wm * 64;
    const int no   = nt * BN + wn * 64;
    const int h_lo = (nt * BN) / WW;

    const f16x8* ag = (const f16x8*)(wgen2 + (size_t)slice * SLICE_ELEMS)
                      + (wm * 4) * 64 + lane;
    const ushort* xp = xpad + (size_t)b * HP * WP * CIN;

    int p_goff[4], p_loff[4];
    bool p_ok[4];
#pragma unroll
    for (int r = 0; r < 4; ++r) {
        const int j = r * 256 + tid;
        p_ok[r] = (j < 960);
        const int jj  = p_ok[r] ? j : 0;
        const int qc  = jj / 240;
        const int rem = jj % 240;
        const int rr  = rem / 30;
        const int ww  = rem % 30;
        int srow = h_lo + rr;
        if (srow > 29) srow = 29;
        p_goff[r] = (srow * WP + ww) * CIN + qc * 8;
        p_loff[r] = jj * 8;
    }

    int pixbase[4], pst[4];
#pragma unroll
    for (int j = 0; j < 4; ++j) {
        const int p  = no + j * 16 + col;
        pst[j] = p;
        const int pc = p > (NPIX - 1) ? (NPIX - 1) : p;
        pixbase[j] = (pc / WW - h_lo) * 30 + (pc % WW);
    }

    f32x4 acc[4][4];
#pragma unroll
    for (int mi = 0; mi < 4; ++mi)
#pragma unroll
        for (int nj = 0; nj < 4; ++nj)
            acc[mi][nj] = (f32x4){0.f, 0.f, 0.f, 0.f};

    for (int c32 = 0; c32 < 8; ++c32) {
        __syncthreads();

#pragma unroll
        for (int r = 0; r < 4; ++r)
            if (p_ok[r]) gll16(xp + p_goff[r] + c32 * 32, Psh + p_loff[r]);
        __syncthreads();

#pragma unroll
        for (int khw = 0; khw < 9; ++khw) {
            const f16x8* a0 = ag + ((c32 * 9 + khw) << 9);
            f16x8 af[4];
#pragma unroll
            for (int mi = 0; mi < 4; ++mi)
                af[mi] = a0[mi * 64];

            const int koff = (khw / 3) * 30 + (khw % 3);
            f16x8 bf[4];
#pragma unroll
            for (int j = 0; j < 4; ++j)
                bf[j] = ((const f16x8*)Psh)[quad * 240 + pixbase[j] + koff];

#pragma unroll
            for (int mi = 0; mi < 4; ++mi)
#pragma unroll
                for (int nj = 0; nj < 4; ++nj)
                    acc[mi][nj] = __builtin_amdgcn_mfma_f32_16x16x32_f16(
                        af[mi], bf[nj], acc[mi][nj], 0, 0, 0);
        }
    }

    float* ob = out + (size_t)b * COUT * NPIX;
#pragma unroll
    for (int mi = 0; mi < 4; ++mi) {
        const int m = mo + mi * 16 + quad * 4;
        const float4 bv = *(const float4*)(bias + m);
#pragma unroll
        for (int nj = 0; nj < 4; ++nj) {
            const int p = pst[nj];
            if (p < NPIX) {
                ob[(size_t)(m + 0) * NPIX + p] = acc[mi][nj][0] + bv.x;
                ob[(size_t)(m + 1) * NPIX + p] = acc[mi][nj][1] + bv.y;
                ob[(size_t)(m + 2) * NPIX + p] = acc[mi][nj][2] + bv.z;
                ob[(size_t)(m + 3) * NPIX + p] = acc[mi][nj][3] + bv.w;
            }
        }
    }
}

extern "C" void kernel_launch(void* const* d_in, const int* in_sizes, int n_in,
                              void* d_out, int out_size, void* d_ws, size_t ws_size,
                              hipStream_t stream) {
    const float* x      = (const float*)d_in[0];
    const float* se     = (const float*)d_in[1];
    const float* weight = (const float*)d_in[2];
    const float* bias   = (const float*)d_in[3];
    float* out          = (float*)d_out;

    ushort* wgen2 = (ushort*)d_ws;
    ushort* xpad  = (ushort*)d_ws + XPAD_OFF;
    (void)ws_size; (void)in_sizes; (void)n_in; (void)out_size;

    prep<<<dim3(PREP_GRID), dim3(256), 0, stream>>>(weight, se, x, wgen2, xpad);
    dconv_mfma<<<dim3(BB * 2 * NT), dim3(256), 0, stream>>>(wgen2, xpad, bias, out);
}

// Round 10
// 151.338 us; speedup vs baseline: 1.1807x; 1.0034x over previous
//
#include <hip/hip_runtime.h>
#include <hip/hip_fp16.h>

#define BB    32
#define CIN   256
#define COUT  256
#define HH    28
#define WW    28
#define NPIX  784
#define HP    30
#define WP    30

#define BM    128
#define BN    128
#define NT    7               // ceil(784/128)

// workspace:
//   wgen2: fragment-ordered filters, per (b,mt) slice 294912 f16 elems
//          (= 128 m-rows x 2304 K). Chunk index (in 8-f16 units):
//          (c32*9 + khw)*512 + sub*64 + quad*16 + col
//   xpad : [b][30][30][256] f16 zero-padded NHWC
#define SLICE_ELEMS 294912                       // 128 * 2304
#define WGEN_ELEMS  ((size_t)BB * 2 * SLICE_ELEMS)
#define XPAD_OFF    (WGEN_ELEMS)

#define PREP_GENW  256        // (og 0..31) x (c32 0..7)
#define PREP_GENX  960
#define PREP_GRID  (PREP_GENW + PREP_GENX)

typedef _Float16 f16x8 __attribute__((ext_vector_type(8)));
typedef float    f32x4 __attribute__((ext_vector_type(4)));

static __device__ __forceinline__ ushort f2h_bits(float v) {
    __half h = __float2half(v);
    return *reinterpret_cast<ushort*>(&h);
}

static __device__ __forceinline__ void gll16(const ushort* g, ushort* l) {
    __builtin_amdgcn_global_load_lds(
        (const __attribute__((address_space(1))) unsigned int*)g,
        (__attribute__((address_space(3))) unsigned int*)l, 16, 0, 0);
}

// ---------------------------------------------------------------------------
// Fused prep kernel (unchanged from round 9).
// ---------------------------------------------------------------------------
__global__ __launch_bounds__(256) void prep(const float* __restrict__ weight,
                                            const float* __restrict__ se,
                                            const float* __restrict__ x,
                                            ushort* __restrict__ wgen2,
                                            ushort* __restrict__ xpad) {
    __shared__ __align__(16) char smem[29696];
    const int bid = blockIdx.x;
    const int tid = threadIdx.x;

    if (bid < PREP_GENW) {
        // ---- gen_w V3: register-resident, read-once, coalesced stores ----
        const int og  = bid >> 3;
        const int c32 = bid & 7;
        const int ol  = tid >> 5;
        const int cl  = tid & 31;
        const int o   = og * 8 + ol;
        const int c   = c32 * 32 + cl;

        float*  se_sh = (float*)smem;                 // 1024 B
        ushort* w_lds = (ushort*)(smem + 1024);       // [khw*8+ol][40], 11520 B

        se_sh[tid] = se[tid];

        float4 wr[18];
        const float4* wp = (const float4*)(weight + ((size_t)o * CIN + c) * 72);
#pragma unroll
        for (int i = 0; i < 18; ++i) wr[i] = wp[i];

        const int khw0 = tid >> 5;
        const int q0   = (tid >> 3) & 3;
        const int ol0  = tid & 7;
        const int khw1 = 8;
        const int q1   = (tid >> 3) & 3;
        const int ol1  = tid & 7;
        const int o0   = og * 8 + ol0;
        const int sub0 = (o0 >> 4) & 7, col0 = o0 & 15;
        const int o1   = og * 8 + ol1;
        const int sub1 = (o1 >> 4) & 7, col1 = o1 & 15;
        const int mt0  = o0 >> 7;    // og fixed => all o in block share mt
        const int dst0 = ((c32 * 9 + khw0) * 512 + sub0 * 64 + q0 * 16 + col0) * 8;
        const int dst1 = ((c32 * 9 + khw1) * 512 + sub1 * 64 + q1 * 16 + col1) * 8;
        const int src0 = (khw0 * 8 + ol0) * 40 + q0 * 8;
        const int src1 = (khw1 * 8 + ol1) * 40 + q1 * 8;

        __syncthreads();

        for (int b = 0; b < BB; ++b) {
            const float s0 = se_sh[b * 8 + 0], s1 = se_sh[b * 8 + 1];
            const float s2 = se_sh[b * 8 + 2], s3 = se_sh[b * 8 + 3];
            const float s4 = se_sh[b * 8 + 4], s5 = se_sh[b * 8 + 5];
            const float s6 = se_sh[b * 8 + 6], s7 = se_sh[b * 8 + 7];
#pragma unroll
            for (int k = 0; k < 9; ++k) {
                const float4 w0 = wr[2 * k + 0];
                const float4 w1 = wr[2 * k + 1];
                const float v = w0.x * s0 + w0.y * s1 + w0.z * s2 + w0.w * s3
                              + w1.x * s4 + w1.y * s5 + w1.z * s6 + w1.w * s7;
                w_lds[(k * 8 + ol) * 40 + cl] = f2h_bits(v);
            }
            __syncthreads();
            ushort* slice_base = wgen2 + (size_t)(b * 2 + mt0) * SLICE_ELEMS;
            *(uint4*)(slice_base + dst0) = *(const uint4*)(w_lds + src0);
            if (tid < 32)
                *(uint4*)(slice_base + dst1) = *(const uint4*)(w_lds + src1);
            __syncthreads();
        }
    } else {
        // ---- gen_x ----
        const int idx = bid - PREP_GENW;
        const int hp  = idx % HP;
        const int b   = idx / HP;
        ushort* row = xpad + ((size_t)b * HP + hp) * WP * CIN;

        if (hp == 0 || hp == HP - 1) {
            uint* r32 = (uint*)row;
            for (int i = tid; i < (WP * CIN) / 2; i += 256) r32[i] = 0u;
            return;
        }
        {
            uint* c0 = (uint*)row;
            uint* c1 = (uint*)(row + (WP - 1) * CIN);
            if (tid < 128)       c0[tid] = 0u;
            else                 c1[tid - 128] = 0u;
        }
        float* lds = (float*)smem;
        const int h = hp - 1;
        const float* xr = x + (size_t)b * CIN * NPIX + h * WW;

        for (int f = tid; f < CIN * WW; f += 256) {
            const int c = f / WW;
            const int w = f % WW;
            lds[c * (WW + 1) + w] = xr[(size_t)c * NPIX + w];
        }
        __syncthreads();
        for (int g2 = tid; g2 < WW * CIN; g2 += 256) {
            const int w = g2 >> 8;
            const int c = g2 & 255;
            row[(w + 1) * CIN + c] = f2h_bits(lds[c * (WW + 1) + w]);
        }
    }
}

// ---------------------------------------------------------------------------
// dconv: implicit-GEMM, fully software-pipelined.
//  - Psh double-buffered: ONE barrier per c32; next c32's patch staged via
//    global_load_lds immediately after the barrier, hidden behind 9-khw compute.
//  - A-fragment ring (3 slots, issue distance 2): 8 global dwordx4 always in
//    flight; slot index = khw%3 (constant-folds; 9%3==0 keeps ring seamless
//    across c32 boundaries).
//  - bf ring (2 slots, distance 1) for LDS reads.
// Block tile 128x128, wave 64x64, grid 448, XCD-grouped.
// ---------------------------------------------------------------------------
#define KOFF(k) (((k) / 3) * 30 + ((k) % 3))

__global__ __launch_bounds__(256, 2) void dconv_mfma(const ushort* __restrict__ wgen2,
                                                     const ushort* __restrict__ xpad,
                                                     const float* __restrict__ bias,
                                                     float* __restrict__ out) {
    const int bid   = blockIdx.x;
    const int g     = bid & 7;
    const int s     = bid >> 3;            // 0..55
    const int nt    = s % NT;
    const int slice = g + 8 * (s / NT);    // 0..63 = b*2 + mt
    const int b     = slice >> 1;
    const int mt    = slice & 1;

    const int tid  = threadIdx.x;
    const int lane = tid & 63;
    const int wave = tid >> 6;
    const int wm   = wave >> 1;
    const int wn   = wave & 1;
    const int col  = lane & 15;
    const int quad = lane >> 4;

    __shared__ ushort Psh[2][7680];        // 2 x 15360 B: [quad][row][w][8 f16]

    const int mo   = mt * BM + wm * 64;
    const int no   = nt * BN + wn * 64;
    const int h_lo = (nt * BN) / WW;

    const f16x8* ag = (const f16x8*)(wgen2 + (size_t)slice * SLICE_ELEMS)
                      + (wm * 4) * 64 + lane;
    const ushort* xp = xpad + (size_t)b * HP * WP * CIN;

    int p_goff[4], p_loff[4];
    bool p_ok[4];
#pragma unroll
    for (int r = 0; r < 4; ++r) {
        const int j = r * 256 + tid;
        p_ok[r] = (j < 960);
        const int jj  = p_ok[r] ? j : 0;
        const int qc  = jj / 240;
        const int rem = jj % 240;
        const int rr  = rem / 30;
        const int ww  = rem % 30;
        int srow = h_lo + rr;
        if (srow > 29) srow = 29;
        p_goff[r] = (srow * WP + ww) * CIN + qc * 8;
        p_loff[r] = jj * 8;
    }

    int pixbase[4], pst[4];
#pragma unroll
    for (int j = 0; j < 4; ++j) {
        const int p  = no + j * 16 + col;
        pst[j] = p;
        const int pc = p > (NPIX - 1) ? (NPIX - 1) : p;
        pixbase[j] = (pc / WW - h_lo) * 30 + (pc % WW);
    }

    f32x4 acc[4][4];
#pragma unroll
    for (int mi = 0; mi < 4; ++mi)
#pragma unroll
        for (int nj = 0; nj < 4; ++nj)
            acc[mi][nj] = (f32x4){0.f, 0.f, 0.f, 0.f};

    // ---- prologue ----
    // patch c32=0 -> Psh[0]
#pragma unroll
    for (int r = 0; r < 4; ++r)
        if (p_ok[r]) gll16(xp + p_goff[r], &Psh[0][p_loff[r]]);

    // A ring: slots for s=0 (slot 0) and s=1 (slot 1)
    f16x8 afr[3][4];
#pragma unroll
    for (int mi = 0; mi < 4; ++mi) afr[0][mi] = ag[mi * 64];
    {
        const f16x8* a1 = ag + (1 << 9);
#pragma unroll
        for (int mi = 0; mi < 4; ++mi) afr[1][mi] = a1[mi * 64];
    }

    f16x8 bfr[2][4];

    for (int c32 = 0; c32 < 8; ++c32) {
        __syncthreads();   // patch(c32) resident; all waves done reading Psh[(c32+1)&1]

        // issue next patch into the other buffer (hidden behind this c32's compute)
        if (c32 < 7) {
            const int nb = (c32 + 1) & 1;
#pragma unroll
            for (int r = 0; r < 4; ++r)
                if (p_ok[r]) gll16(xp + p_goff[r] + (c32 + 1) * 32,
                                   &Psh[nb][p_loff[r]]);
        }

        const f16x8* Pc = (const f16x8*)Psh[c32 & 1];

        // bf for khw=0 into slot 0
#pragma unroll
        for (int j = 0; j < 4; ++j)
            bfr[0][j] = Pc[quad * 240 + pixbase[j] + KOFF(0)];

#pragma unroll
        for (int khw = 0; khw < 9; ++khw) {
            const int st = c32 * 9 + khw;
            // A prefetch, distance 2
            int sp = st + 2; if (sp > 71) sp = 71;
            const f16x8* apf = ag + ((size_t)sp << 9);
#pragma unroll
            for (int mi = 0; mi < 4; ++mi)
                afr[(khw + 2) % 3][mi] = apf[mi * 64];
            // bf prefetch, distance 1 (within this c32)
            if (khw < 8) {
#pragma unroll
                for (int j = 0; j < 4; ++j)
                    bfr[(khw + 1) & 1][j] = Pc[quad * 240 + pixbase[j] + KOFF(khw + 1)];
            }
            // consume
#pragma unroll
            for (int mi = 0; mi < 4; ++mi)
#pragma unroll
                for (int nj = 0; nj < 4; ++nj)
                    acc[mi][nj] = __builtin_amdgcn_mfma_f32_16x16x32_f16(
                        afr[khw % 3][mi], bfr[khw & 1][nj], acc[mi][nj], 0, 0, 0);
        }
    }

    // ---- epilogue ----
    float* ob = out + (size_t)b * COUT * NPIX;
#pragma unroll
    for (int mi = 0; mi < 4; ++mi) {
        const int m = mo + mi * 16 + quad * 4;
        const float4 bv = *(const float4*)(bias + m);
#pragma unroll
        for (int nj = 0; nj < 4; ++nj) {
            const int p = pst[nj];
            if (p < NPIX) {
                ob[(size_t)(m + 0) * NPIX + p] = acc[mi][nj][0] + bv.x;
                ob[(size_t)(m + 1) * NPIX + p] = acc[mi][nj][1] + bv.y;
                ob[(size_t)(m + 2) * NPIX + p] = acc[mi][nj][2] + bv.z;
                ob[(size_t)(m + 3) * NPIX + p] = acc[mi][nj][3] + bv.w;
            }
        }
    }
}

extern "C" void kernel_launch(void* const* d_in, const int* in_sizes, int n_in,
                              void* d_out, int out_size, void* d_ws, size_t ws_size,
                              hipStream_t stream) {
    const float* x      = (const float*)d_in[0];
    const float* se     = (const float*)d_in[1];
    const float* weight = (const float*)d_in[2];
    const float* bias   = (const float*)d_in[3];
    float* out          = (float*)d_out;

    ushort* wgen2 = (ushort*)d_ws;
    ushort* xpad  = (ushort*)d_ws + XPAD_OFF;
    (void)ws_size; (void)in_sizes; (void)n_in; (void)out_size;

    prep<<<dim3(PREP_GRID), dim3(256), 0, stream>>>(weight, se, x, wgen2, xpad);
    dconv_mfma<<<dim3(BB * 2 * NT), dim3(256), 0, stream>>>(wgen2, xpad, bias, out);
}

// Round 11
// 148.513 us; speedup vs baseline: 1.2032x; 1.0190x over previous
//
#include <hip/hip_runtime.h>
#include <hip/hip_fp16.h>

#define BB    32
#define CIN   256
#define COUT  256
#define HH    28
#define WW    28
#define NPIX  784
#define HP    30
#define WP    30

#define BM    64
#define BN    128
#define NT    7               // 784 / 128 (ceil)

// workspace:
//   wgen2: fragment-ordered filters, per (b,mtH) slice 294912 f16 elems
//          (= 128 m-rows x 2304 K). Chunk index (in 8-f16 units):
//          (c32*9 + khw)*512 + sub*64 + quad*16 + col
//          holds A[m = mtH*128 + sub*16 + col][ch = c32*32 + quad*8 .. +7]
//   xpad : [b][30][30][256] f16 zero-padded NHWC
#define SLICE_ELEMS 294912                       // 128 * 2304
#define WGEN_ELEMS  ((size_t)BB * 2 * SLICE_ELEMS)
#define XPAD_OFF    (WGEN_ELEMS)

#define PREP_GENW  256        // (og 0..31) x (c32 0..7)
#define PREP_GENX  960
#define PREP_GRID  (PREP_GENW + PREP_GENX)

typedef _Float16 f16x8 __attribute__((ext_vector_type(8)));
typedef float    f32x4 __attribute__((ext_vector_type(4)));

static __device__ __forceinline__ ushort f2h_bits(float v) {
    __half h = __float2half(v);
    return *reinterpret_cast<ushort*>(&h);
}

static __device__ __forceinline__ void gll16(const ushort* g, ushort* l) {
    __builtin_amdgcn_global_load_lds(
        (const __attribute__((address_space(1))) unsigned int*)g,
        (__attribute__((address_space(3))) unsigned int*)l, 16, 0, 0);
}

// ---------------------------------------------------------------------------
// Fused prep kernel (unchanged from round 9/10).
// ---------------------------------------------------------------------------
__global__ __launch_bounds__(256) void prep(const float* __restrict__ weight,
                                            const float* __restrict__ se,
                                            const float* __restrict__ x,
                                            ushort* __restrict__ wgen2,
                                            ushort* __restrict__ xpad) {
    __shared__ __align__(16) char smem[29696];
    const int bid = blockIdx.x;
    const int tid = threadIdx.x;

    if (bid < PREP_GENW) {
        // ---- gen_w V3: register-resident, read-once, coalesced stores ----
        const int og  = bid >> 3;
        const int c32 = bid & 7;
        const int ol  = tid >> 5;
        const int cl  = tid & 31;
        const int o   = og * 8 + ol;
        const int c   = c32 * 32 + cl;

        float*  se_sh = (float*)smem;                 // 1024 B
        ushort* w_lds = (ushort*)(smem + 1024);       // [khw*8+ol][40], 11520 B

        se_sh[tid] = se[tid];

        float4 wr[18];
        const float4* wp = (const float4*)(weight + ((size_t)o * CIN + c) * 72);
#pragma unroll
        for (int i = 0; i < 18; ++i) wr[i] = wp[i];

        const int khw0 = tid >> 5;
        const int q0   = (tid >> 3) & 3;
        const int ol0  = tid & 7;
        const int khw1 = 8;
        const int q1   = (tid >> 3) & 3;
        const int ol1  = tid & 7;
        const int o0   = og * 8 + ol0;
        const int sub0 = (o0 >> 4) & 7, col0 = o0 & 15;
        const int o1   = og * 8 + ol1;
        const int sub1 = (o1 >> 4) & 7, col1 = o1 & 15;
        const int mt0  = o0 >> 7;
        const int dst0 = ((c32 * 9 + khw0) * 512 + sub0 * 64 + q0 * 16 + col0) * 8;
        const int dst1 = ((c32 * 9 + khw1) * 512 + sub1 * 64 + q1 * 16 + col1) * 8;
        const int src0 = (khw0 * 8 + ol0) * 40 + q0 * 8;
        const int src1 = (khw1 * 8 + ol1) * 40 + q1 * 8;

        __syncthreads();

        for (int b = 0; b < BB; ++b) {
            const float s0 = se_sh[b * 8 + 0], s1 = se_sh[b * 8 + 1];
            const float s2 = se_sh[b * 8 + 2], s3 = se_sh[b * 8 + 3];
            const float s4 = se_sh[b * 8 + 4], s5 = se_sh[b * 8 + 5];
            const float s6 = se_sh[b * 8 + 6], s7 = se_sh[b * 8 + 7];
#pragma unroll
            for (int k = 0; k < 9; ++k) {
                const float4 w0 = wr[2 * k + 0];
                const float4 w1 = wr[2 * k + 1];
                const float v = w0.x * s0 + w0.y * s1 + w0.z * s2 + w0.w * s3
                              + w1.x * s4 + w1.y * s5 + w1.z * s6 + w1.w * s7;
                w_lds[(k * 8 + ol) * 40 + cl] = f2h_bits(v);
            }
            __syncthreads();
            ushort* slice_base = wgen2 + (size_t)(b * 2 + mt0) * SLICE_ELEMS;
            *(uint4*)(slice_base + dst0) = *(const uint4*)(w_lds + src0);
            if (tid < 32)
                *(uint4*)(slice_base + dst1) = *(const uint4*)(w_lds + src1);
            __syncthreads();
        }
    } else {
        // ---- gen_x ----
        const int idx = bid - PREP_GENW;
        const int hp  = idx % HP;
        const int b   = idx / HP;
        ushort* row = xpad + ((size_t)b * HP + hp) * WP * CIN;

        if (hp == 0 || hp == HP - 1) {
            uint* r32 = (uint*)row;
            for (int i = tid; i < (WP * CIN) / 2; i += 256) r32[i] = 0u;
            return;
        }
        {
            uint* c0 = (uint*)row;
            uint* c1 = (uint*)(row + (WP - 1) * CIN);
            if (tid < 128)       c0[tid] = 0u;
            else                 c1[tid - 128] = 0u;
        }
        float* lds = (float*)smem;
        const int h = hp - 1;
        const float* xr = x + (size_t)b * CIN * NPIX + h * WW;

        for (int f = tid; f < CIN * WW; f += 256) {
            const int c = f / WW;
            const int w = f % WW;
            lds[c * (WW + 1) + w] = xr[(size_t)c * NPIX + w];
        }
        __syncthreads();
        for (int g2 = tid; g2 < WW * CIN; g2 += 256) {
            const int w = g2 >> 8;
            const int c = g2 & 255;
            row[(w + 1) * CIN + c] = f2h_bits(lds[c * (WW + 1) + w]);
        }
    }
}

// ---------------------------------------------------------------------------
// dconv: implicit-GEMM, BM=64 for 2x TLP (896 blocks = 3.5/CU = 14 waves/CU).
// Wave tile 32x64: 8 MFMA, 2 A-loads, 4 bf reads per step. Psh double-buffered
// (1 barrier/c32); A-ring 3 slots distance 2. XCD remap groups the 14 blocks
// sharing one wgen2 slice (b, mtH) on one XCD.
// ---------------------------------------------------------------------------
#define KOFF(k) (((k) / 3) * 30 + ((k) % 3))

__global__ __launch_bounds__(256, 4) void dconv_mfma(const ushort* __restrict__ wgen2,
                                                     const ushort* __restrict__ xpad,
                                                     const float* __restrict__ bias,
                                                     float* __restrict__ out) {
    // 896 = 8 XCD-groups x 112; within a group: 8 slice2 x (2 mtl x 7 nt)
    const int bid    = blockIdx.x;
    const int g      = bid & 7;
    const int s      = bid >> 3;           // 0..111
    const int t      = s % 14;
    const int nt     = t % 7;
    const int mtl    = t / 7;              // low half-select within slice
    const int slice2 = g + 8 * (s / 14);   // 0..63 = b*2 + mtH
    const int b      = slice2 >> 1;
    const int mtH    = slice2 & 1;

    const int tid  = threadIdx.x;
    const int lane = tid & 63;
    const int wave = tid >> 6;
    const int wm   = wave >> 1;            // 0..1 -> m sub-half
    const int wn   = wave & 1;             // 0..1 -> n half
    const int col  = lane & 15;
    const int quad = lane >> 4;

    __shared__ ushort Psh[2][7680];        // 2 x 15360 B: [quad][row][w][8 f16]

    const int mo   = mtH * 128 + mtl * 64 + wm * 32;
    const int no   = nt * BN + wn * 64;
    const int h_lo = (nt * BN) / WW;

    // A: fragment-ordered slice (b, mtH); this wave covers subs mtl*4+wm*2+{0,1}
    const f16x8* ag = (const f16x8*)(wgen2 + (size_t)slice2 * SLICE_ELEMS)
                      + (mtl * 4 + wm * 2) * 64 + lane;
    const ushort* xp = xpad + (size_t)b * HP * WP * CIN;

    int p_goff[4], p_loff[4];
    bool p_ok[4];
#pragma unroll
    for (int r = 0; r < 4; ++r) {
        const int j = r * 256 + tid;
        p_ok[r] = (j < 960);
        const int jj  = p_ok[r] ? j : 0;
        const int qc  = jj / 240;
        const int rem = jj % 240;
        const int rr  = rem / 30;
        const int ww  = rem % 30;
        int srow = h_lo + rr;
        if (srow > 29) srow = 29;
        p_goff[r] = (srow * WP + ww) * CIN + qc * 8;
        p_loff[r] = jj * 8;
    }

    int pixbase[4], pst[4];
#pragma unroll
    for (int j = 0; j < 4; ++j) {
        const int p  = no + j * 16 + col;
        pst[j] = p;
        const int pc = p > (NPIX - 1) ? (NPIX - 1) : p;
        pixbase[j] = (pc / WW - h_lo) * 30 + (pc % WW);
    }

    f32x4 acc[2][4];
#pragma unroll
    for (int mi = 0; mi < 2; ++mi)
#pragma unroll
        for (int nj = 0; nj < 4; ++nj)
            acc[mi][nj] = (f32x4){0.f, 0.f, 0.f, 0.f};

    // ---- prologue ----
#pragma unroll
    for (int r = 0; r < 4; ++r)
        if (p_ok[r]) gll16(xp + p_goff[r], &Psh[0][p_loff[r]]);

    f16x8 afr[3][2];
#pragma unroll
    for (int mi = 0; mi < 2; ++mi) afr[0][mi] = ag[mi * 64];
    {
        const f16x8* a1 = ag + (1 << 9);
#pragma unroll
        for (int mi = 0; mi < 2; ++mi) afr[1][mi] = a1[mi * 64];
    }

    f16x8 bfr[2][4];

    for (int c32 = 0; c32 < 8; ++c32) {
        __syncthreads();   // patch(c32) resident; prev buffer free

        if (c32 < 7) {
            const int nb = (c32 + 1) & 1;
#pragma unroll
            for (int r = 0; r < 4; ++r)
                if (p_ok[r]) gll16(xp + p_goff[r] + (c32 + 1) * 32,
                                   &Psh[nb][p_loff[r]]);
        }

        const f16x8* Pc = (const f16x8*)Psh[c32 & 1];

#pragma unroll
        for (int j = 0; j < 4; ++j)
            bfr[0][j] = Pc[quad * 240 + pixbase[j] + KOFF(0)];

#pragma unroll
        for (int khw = 0; khw < 9; ++khw) {
            const int st = c32 * 9 + khw;
            int sp = st + 2; if (sp > 71) sp = 71;
            const f16x8* apf = ag + ((size_t)sp << 9);
#pragma unroll
            for (int mi = 0; mi < 2; ++mi)
                afr[(khw + 2) % 3][mi] = apf[mi * 64];
            if (khw < 8) {
#pragma unroll
                for (int j = 0; j < 4; ++j)
                    bfr[(khw + 1) & 1][j] = Pc[quad * 240 + pixbase[j] + KOFF(khw + 1)];
            }
#pragma unroll
            for (int mi = 0; mi < 2; ++mi)
#pragma unroll
                for (int nj = 0; nj < 4; ++nj)
                    acc[mi][nj] = __builtin_amdgcn_mfma_f32_16x16x32_f16(
                        afr[khw % 3][mi], bfr[khw & 1][nj], acc[mi][nj], 0, 0, 0);
        }
    }

    // ---- epilogue ----
    float* ob = out + (size_t)b * COUT * NPIX;
#pragma unroll
    for (int mi = 0; mi < 2; ++mi) {
        const int m = mo + mi * 16 + quad * 4;
        const float4 bv = *(const float4*)(bias + m);
#pragma unroll
        for (int nj = 0; nj < 4; ++nj) {
            const int p = pst[nj];
            if (p < NPIX) {
                ob[(size_t)(m + 0) * NPIX + p] = acc[mi][nj][0] + bv.x;
                ob[(size_t)(m + 1) * NPIX + p] = acc[mi][nj][1] + bv.y;
                ob[(size_t)(m + 2) * NPIX + p] = acc[mi][nj][2] + bv.z;
                ob[(size_t)(m + 3) * NPIX + p] = acc[mi][nj][3] + bv.w;
            }
        }
    }
}

extern "C" void kernel_launch(void* const* d_in, const int* in_sizes, int n_in,
                              void* d_out, int out_size, void* d_ws, size_t ws_size,
                              hipStream_t stream) {
    const float* x      = (const float*)d_in[0];
    const float* se     = (const float*)d_in[1];
    const float* weight = (const float*)d_in[2];
    const float* bias   = (const float*)d_in[3];
    float* out          = (float*)d_out;

    ushort* wgen2 = (ushort*)d_ws;
    ushort* xpad  = (ushort*)d_ws + XPAD_OFF;
    (void)ws_size; (void)in_sizes; (void)n_in; (void)out_size;

    prep<<<dim3(PREP_GRID), dim3(256), 0, stream>>>(weight, se, x, wgen2, xpad);
    dconv_mfma<<<dim3(BB * 4 * NT), dim3(256), 0, stream>>>(wgen2, xpad, bias, out);
}